// Round 3
// baseline (714.182 us; speedup 1.0000x reference)
//
#include <hip/hip_runtime.h>

#define N_NODES 100000
#define D_IN 32
#define H 64
#define EPS 1e-5f

#define PSZ 256                          // nodes per partition
#define NP ((N_NODES + PSZ - 1) / PSZ)   // 391 partitions
#define STRIDE 4096                      // entries per partition region (mean 3197, +15.9 sigma)
#define BATCH 8192                       // edges per block in bin_kernel
#define EPT (BATCH / 256)                // 32 edges per thread
#define OV_CAP 65536
#define COL_MASK 0x1FFFF                 // 17 bits for col (N_NODES < 2^17)

// ---------------- node MLP: thread-per-node ----------------
// Weight reads are wave-uniform (scalarized to s_load); LN is per-lane math.
__global__ __launch_bounds__(256) void mlp_kernel(
    const float* __restrict__ x,
    const float* __restrict__ W1, const float* __restrict__ b1,
    const float* __restrict__ g1, const float* __restrict__ be1,
    const float* __restrict__ W2, const float* __restrict__ b2,
    const float* __restrict__ g2, const float* __restrict__ be2,
    float* __restrict__ h)
{
    int node = blockIdx.x * blockDim.x + threadIdx.x;
    if (node >= N_NODES) return;

    float xr[D_IN];
    {
        const float4* xp = (const float4*)(x + (long long)node * D_IN);
#pragma unroll
        for (int i = 0; i < D_IN / 4; ++i) {
            float4 v = xp[i];
            xr[4*i+0] = v.x; xr[4*i+1] = v.y; xr[4*i+2] = v.z; xr[4*i+3] = v.w;
        }
    }

    float h1[H];
#pragma unroll
    for (int jb = 0; jb < H / 4; ++jb) {
        float4 b = *(const float4*)(b1 + jb * 4);
        h1[4*jb+0] = b.x; h1[4*jb+1] = b.y; h1[4*jb+2] = b.z; h1[4*jb+3] = b.w;
    }
#pragma unroll
    for (int k = 0; k < D_IN; ++k) {
        float xk = xr[k];
#pragma unroll
        for (int jb = 0; jb < H / 4; ++jb) {
            float4 w = *(const float4*)(W1 + k * H + jb * 4);
            h1[4*jb+0] += xk * w.x; h1[4*jb+1] += xk * w.y;
            h1[4*jb+2] += xk * w.z; h1[4*jb+3] += xk * w.w;
        }
    }
    {
        float s0=0,s1=0,s2=0,s3=0, q0=0,q1=0,q2=0,q3=0;
#pragma unroll
        for (int j = 0; j < H; j += 4) {
            s0 += h1[j+0]; s1 += h1[j+1]; s2 += h1[j+2]; s3 += h1[j+3];
            q0 += h1[j+0]*h1[j+0]; q1 += h1[j+1]*h1[j+1];
            q2 += h1[j+2]*h1[j+2]; q3 += h1[j+3]*h1[j+3];
        }
        float mu  = (s0+s1+s2+s3) * (1.0f / H);
        float var = (q0+q1+q2+q3) * (1.0f / H) - mu * mu;
        float rs  = rsqrtf(var + EPS);
#pragma unroll
        for (int jb = 0; jb < H / 4; ++jb) {
            float4 g = *(const float4*)(g1 + jb * 4);
            float4 be = *(const float4*)(be1 + jb * 4);
            h1[4*jb+0] = fmaxf((h1[4*jb+0]-mu)*rs*g.x + be.x, 0.0f);
            h1[4*jb+1] = fmaxf((h1[4*jb+1]-mu)*rs*g.y + be.y, 0.0f);
            h1[4*jb+2] = fmaxf((h1[4*jb+2]-mu)*rs*g.z + be.z, 0.0f);
            h1[4*jb+3] = fmaxf((h1[4*jb+3]-mu)*rs*g.w + be.w, 0.0f);
        }
    }

    float h2[H];
#pragma unroll
    for (int jb = 0; jb < H / 4; ++jb) {
        float4 b = *(const float4*)(b2 + jb * 4);
        h2[4*jb+0] = b.x; h2[4*jb+1] = b.y; h2[4*jb+2] = b.z; h2[4*jb+3] = b.w;
    }
#pragma unroll
    for (int k = 0; k < H; ++k) {
        float hk = h1[k];
#pragma unroll
        for (int jb = 0; jb < H / 4; ++jb) {
            float4 w = *(const float4*)(W2 + k * H + jb * 4);
            h2[4*jb+0] += hk * w.x; h2[4*jb+1] += hk * w.y;
            h2[4*jb+2] += hk * w.z; h2[4*jb+3] += hk * w.w;
        }
    }
    {
        float s0=0,s1=0,s2=0,s3=0, q0=0,q1=0,q2=0,q3=0;
#pragma unroll
        for (int j = 0; j < H; j += 4) {
            s0 += h2[j+0]; s1 += h2[j+1]; s2 += h2[j+2]; s3 += h2[j+3];
            q0 += h2[j+0]*h2[j+0]; q1 += h2[j+1]*h2[j+1];
            q2 += h2[j+2]*h2[j+2]; q3 += h2[j+3]*h2[j+3];
        }
        float mu  = (s0+s1+s2+s3) * (1.0f / H);
        float var = (q0+q1+q2+q3) * (1.0f / H) - mu * mu;
        float rs  = rsqrtf(var + EPS);

        float* hp = h + (long long)node * H;
#pragma unroll
        for (int jb = 0; jb < H / 4; ++jb) {
            float4 g = *(const float4*)(g2 + jb * 4);
            float4 be = *(const float4*)(be2 + jb * 4);
            float4 v;
            v.x = fmaxf((h2[4*jb+0]-mu)*rs*g.x + be.x, 0.0f);
            v.y = fmaxf((h2[4*jb+1]-mu)*rs*g.y + be.y, 0.0f);
            v.z = fmaxf((h2[4*jb+2]-mu)*rs*g.z + be.z, 0.0f);
            v.w = fmaxf((h2[4*jb+3]-mu)*rs*g.w + be.w, 0.0f);
            *(float4*)(hp + 4*jb) = v;
        }
    }
}

// ---------------- bin edges into per-partition lists ----------------
// Block processes BATCH edges: LDS-rank per partition, one returning global
// atomic per (partition, block), then writes packed entries at consecutive
// addresses -> L2-coalescible runs instead of random 4B scatter.
__global__ __launch_bounds__(256) void bin_kernel(
    const int* __restrict__ ei, int* __restrict__ part,
    int* __restrict__ gcur, int* __restrict__ ovCnt,
    int* __restrict__ ovRow, int* __restrict__ ovCol, int E)
{
    __shared__ int lcnt[NP];
    __shared__ int gbase[NP];
    const int t = threadIdx.x;
    const long long base = (long long)blockIdx.x * BATCH;

    for (int i = t; i < NP; i += 256) lcnt[i] = 0;
    __syncthreads();

    int pp[EPT]; int pos[EPT]; int vv[EPT];
#pragma unroll
    for (int j = 0; j < EPT; ++j) {
        long long e = base + (long long)j * 256 + t;
        if (e < E) {
            int row = ei[e];
            int col = ei[(long long)E + e];
            int p = row >> 8;                       // / PSZ
            pp[j] = p;
            vv[j] = ((row & (PSZ - 1)) << 17) | col;
            pos[j] = atomicAdd(&lcnt[p], 1);        // LDS atomic
        } else pp[j] = -1;
    }
    __syncthreads();

    for (int i = t; i < NP; i += 256) {
        int c = lcnt[i];
        gbase[i] = c ? atomicAdd(&gcur[i], c) : 0;  // few global atomics
    }
    __syncthreads();

#pragma unroll
    for (int j = 0; j < EPT; ++j) {
        if (pp[j] < 0) continue;
        int idx = gbase[pp[j]] + pos[j];
        if (idx < STRIDE) {
            part[pp[j] * STRIDE + idx] = vv[j];
        } else {                                    // ~never (15.9 sigma)
            int s = atomicAdd(ovCnt, 1);
            if (s < OV_CAP) {
                ovRow[s] = (pp[j] << 8) | (vv[j] >> 17);
                ovCol[s] = vv[j] & COL_MASK;
            }
        }
    }
}

// ---------------- aggregate: block per partition, LDS accumulators ----------------
__global__ __launch_bounds__(512) void aggr_kernel(
    const int* __restrict__ part, const int* __restrict__ gcur,
    const float* __restrict__ h, float* __restrict__ out,
    const int* __restrict__ ovCnt, const int* __restrict__ ovRow,
    const int* __restrict__ ovCol)
{
    __shared__ float acc[PSZ * H];                  // 64 KB
    const int t = threadIdx.x;
    const int lane = t & 63;
    const int wave = t >> 6;                        // 0..7
    const int p = blockIdx.x;

    for (int i = t; i < PSZ * H / 4; i += 512)
        ((float4*)acc)[i] = make_float4(0.f, 0.f, 0.f, 0.f);
    __syncthreads();

    int n = gcur[p]; if (n > STRIDE) n = STRIDE;
    const int* pl = part + p * STRIDE;

    for (int i0 = wave * 4; i0 < n; i0 += 32) {
        int m = n - i0; if (m > 4) m = 4;
        int pk[4]; float v[4];
#pragma unroll
        for (int j = 0; j < 4; ++j) if (j < m) pk[j] = pl[i0 + j];
#pragma unroll
        for (int j = 0; j < 4; ++j) if (j < m)
            v[j] = h[(long long)(pk[j] & COL_MASK) * H + lane];   // 4 gathers in flight
#pragma unroll
        for (int j = 0; j < 4; ++j) if (j < m)
            atomicAdd(&acc[(pk[j] >> 17) * H + lane], v[j]);      // ds_add_f32
    }

    // exact overflow drain (normally 0 entries)
    int nov = *ovCnt; if (nov > OV_CAP) nov = OV_CAP;
    if (wave == 0) {
        for (int i = 0; i < nov; ++i) {
            int r = ovRow[i];
            if ((r >> 8) == p) {
                float v = h[(long long)ovCol[i] * H + lane];
                atomicAdd(&acc[(r & (PSZ - 1)) * H + lane], v);
            }
        }
    }
    __syncthreads();

    for (int r = wave; r < PSZ; r += 8) {
        int node = p * PSZ + r;
        if (node < N_NODES)
            out[(long long)node * H + lane] =
                h[(long long)node * H + lane] + acc[r * H + lane];
    }
}

extern "C" void kernel_launch(void* const* d_in, const int* in_sizes, int n_in,
                              void* d_out, int out_size, void* d_ws, size_t ws_size,
                              hipStream_t stream)
{
    const float* x   = (const float*)d_in[0];
    const int*   ei  = (const int*)d_in[1];
    const float* W1  = (const float*)d_in[2];
    const float* b1  = (const float*)d_in[3];
    const float* g1  = (const float*)d_in[4];
    const float* be1 = (const float*)d_in[5];
    const float* W2  = (const float*)d_in[6];
    const float* b2  = (const float*)d_in[7];
    const float* g2  = (const float*)d_in[8];
    const float* be2 = (const float*)d_in[9];

    float* out = (float*)d_out;

    // workspace layout
    char* ws = (char*)d_ws;
    float* h     = (float*)ws;                         // 25,600,000 B
    int*   part  = (int*)(ws + 25600000);              //  6,406,144 B (391*4096*4)
    int*   gcur  = (int*)(ws + 32006144);              //      1,564 B
    int*   ovCnt = (int*)(ws + 32007708);              //          4 B
    int*   ovRow = (int*)(ws + 32007712);              //    262,144 B
    int*   ovCol = (int*)(ws + 32269856);              //    262,144 B

    const int E = in_sizes[1] / 2;

    // zero gcur + ovCnt (contiguous)
    hipMemsetAsync(ws + 32006144, 0, NP * 4 + 4, stream);

    mlp_kernel<<<(N_NODES + 255) / 256, 256, 0, stream>>>(
        x, W1, b1, g1, be1, W2, b2, g2, be2, h);

    bin_kernel<<<(E + BATCH - 1) / BATCH, 256, 0, stream>>>(
        ei, part, gcur, ovCnt, ovRow, ovCol, E);

    aggr_kernel<<<NP, 512, 0, stream>>>(part, gcur, h, out, ovCnt, ovRow, ovCol);
}

// Round 4
// 336.185 us; speedup vs baseline: 2.1244x; 2.1244x over previous
//
#include <hip/hip_runtime.h>

#define N_NODES 100000
#define D_IN 32
#define H 64
#define EPS 1e-5f
#define CAP 32      // bucket capacity per destination node; P(Poisson(12.5) > 32) ~ 7e-7
#define CSTR 16     // counter stride (ints) -> one counter per 64B line

__device__ __forceinline__ unsigned short f2bf(float f) {
    union { float f; unsigned int u; } c; c.f = f;
    unsigned int b = c.u + 0x7FFFu + ((c.u >> 16) & 1u);   // round-to-nearest-even
    return (unsigned short)(b >> 16);
}
__device__ __forceinline__ float bf2f(unsigned short s) {
    union { unsigned int u; float f; } c; c.u = ((unsigned int)s) << 16;
    return c.f;
}

// ---------------- node MLP: thread-per-node, uniform control flow ----------------
// node clamped (not early-returned) so all weight loads sit in uniform CF and
// can scalarize to s_load. Writes fp32 self-term into out and bf16 copy into hb.
__global__ __launch_bounds__(256) void mlp_kernel(
    const float* __restrict__ x,
    const float* __restrict__ W1, const float* __restrict__ b1,
    const float* __restrict__ g1, const float* __restrict__ be1,
    const float* __restrict__ W2, const float* __restrict__ b2,
    const float* __restrict__ g2, const float* __restrict__ be2,
    unsigned short* __restrict__ hb, float* __restrict__ out)
{
    int gid = blockIdx.x * blockDim.x + threadIdx.x;
    int node = gid < N_NODES ? gid : N_NODES - 1;   // dup work for tail; benign same-value stores

    float xr[D_IN];
    {
        const float4* xp = (const float4*)(x + (long long)node * D_IN);
#pragma unroll
        for (int i = 0; i < D_IN / 4; ++i) {
            float4 v = xp[i];
            xr[4*i+0] = v.x; xr[4*i+1] = v.y; xr[4*i+2] = v.z; xr[4*i+3] = v.w;
        }
    }

    float h1[H];
#pragma unroll
    for (int jb = 0; jb < H / 4; ++jb) {
        float4 b = *(const float4*)(b1 + jb * 4);
        h1[4*jb+0] = b.x; h1[4*jb+1] = b.y; h1[4*jb+2] = b.z; h1[4*jb+3] = b.w;
    }
#pragma unroll
    for (int k = 0; k < D_IN; ++k) {
        float xk = xr[k];
#pragma unroll
        for (int jb = 0; jb < H / 4; ++jb) {
            float4 w = *(const float4*)(W1 + k * H + jb * 4);
            h1[4*jb+0] += xk * w.x; h1[4*jb+1] += xk * w.y;
            h1[4*jb+2] += xk * w.z; h1[4*jb+3] += xk * w.w;
        }
    }
    {
        float s0=0,s1=0,s2=0,s3=0, q0=0,q1=0,q2=0,q3=0;
#pragma unroll
        for (int j = 0; j < H; j += 4) {
            s0 += h1[j+0]; s1 += h1[j+1]; s2 += h1[j+2]; s3 += h1[j+3];
            q0 += h1[j+0]*h1[j+0]; q1 += h1[j+1]*h1[j+1];
            q2 += h1[j+2]*h1[j+2]; q3 += h1[j+3]*h1[j+3];
        }
        float mu  = (s0+s1+s2+s3) * (1.0f / H);
        float var = (q0+q1+q2+q3) * (1.0f / H) - mu * mu;
        float rs  = rsqrtf(var + EPS);
#pragma unroll
        for (int jb = 0; jb < H / 4; ++jb) {
            float4 g = *(const float4*)(g1 + jb * 4);
            float4 be = *(const float4*)(be1 + jb * 4);
            h1[4*jb+0] = fmaxf((h1[4*jb+0]-mu)*rs*g.x + be.x, 0.0f);
            h1[4*jb+1] = fmaxf((h1[4*jb+1]-mu)*rs*g.y + be.y, 0.0f);
            h1[4*jb+2] = fmaxf((h1[4*jb+2]-mu)*rs*g.z + be.z, 0.0f);
            h1[4*jb+3] = fmaxf((h1[4*jb+3]-mu)*rs*g.w + be.w, 0.0f);
        }
    }

    float h2[H];
#pragma unroll
    for (int jb = 0; jb < H / 4; ++jb) {
        float4 b = *(const float4*)(b2 + jb * 4);
        h2[4*jb+0] = b.x; h2[4*jb+1] = b.y; h2[4*jb+2] = b.z; h2[4*jb+3] = b.w;
    }
#pragma unroll
    for (int k = 0; k < H; ++k) {
        float hk = h1[k];
#pragma unroll
        for (int jb = 0; jb < H / 4; ++jb) {
            float4 w = *(const float4*)(W2 + k * H + jb * 4);
            h2[4*jb+0] += hk * w.x; h2[4*jb+1] += hk * w.y;
            h2[4*jb+2] += hk * w.z; h2[4*jb+3] += hk * w.w;
        }
    }
    {
        float s0=0,s1=0,s2=0,s3=0, q0=0,q1=0,q2=0,q3=0;
#pragma unroll
        for (int j = 0; j < H; j += 4) {
            s0 += h2[j+0]; s1 += h2[j+1]; s2 += h2[j+2]; s3 += h2[j+3];
            q0 += h2[j+0]*h2[j+0]; q1 += h2[j+1]*h2[j+1];
            q2 += h2[j+2]*h2[j+2]; q3 += h2[j+3]*h2[j+3];
        }
        float mu  = (s0+s1+s2+s3) * (1.0f / H);
        float var = (q0+q1+q2+q3) * (1.0f / H) - mu * mu;
        float rs  = rsqrtf(var + EPS);

        float* op = out + (long long)node * H;
        unsigned short* hp = hb + (long long)node * H;
#pragma unroll
        for (int jb = 0; jb < H / 4; ++jb) {
            float4 g = *(const float4*)(g2 + jb * 4);
            float4 be = *(const float4*)(be2 + jb * 4);
            float4 v;
            v.x = fmaxf((h2[4*jb+0]-mu)*rs*g.x + be.x, 0.0f);
            v.y = fmaxf((h2[4*jb+1]-mu)*rs*g.y + be.y, 0.0f);
            v.z = fmaxf((h2[4*jb+2]-mu)*rs*g.z + be.z, 0.0f);
            v.w = fmaxf((h2[4*jb+3]-mu)*rs*g.w + be.w, 0.0f);
            *(float4*)(op + 4*jb) = v;              // out starts as h (fp32 self term)
            ushort4 u;
            u.x = f2bf(v.x); u.y = f2bf(v.y); u.z = f2bf(v.z); u.w = f2bf(v.w);
            *(ushort4*)(hp + 4*jb) = u;             // bf16 copy for gathers
        }
    }
}

// ---------------- edge scatter: 4 edges/thread, line-padded counters ----------------
__global__ __launch_bounds__(256) void scatter_kernel(
    const int* __restrict__ ei, const unsigned short* __restrict__ hb,
    int* __restrict__ cnt, int* __restrict__ bkt,
    float* __restrict__ out, int E)
{
    int t = blockIdx.x * blockDim.x + threadIdx.x;
    int e0 = t * 4;
    if (e0 >= E) return;

    int rows[4], cols[4], pos[4];
    if (e0 + 3 < E) {
        int4 r = *(const int4*)(ei + e0);
        int4 c = *(const int4*)(ei + E + e0);
        rows[0]=r.x; rows[1]=r.y; rows[2]=r.z; rows[3]=r.w;
        cols[0]=c.x; cols[1]=c.y; cols[2]=c.z; cols[3]=c.w;
    } else {
#pragma unroll
        for (int j = 0; j < 4; ++j) {
            int e = e0 + j;
            if (e < E) { rows[j] = ei[e]; cols[j] = ei[E + e]; }
            else rows[j] = -1;
        }
    }
    // 4 independent returning atomics in flight (one counter per 64B line)
#pragma unroll
    for (int j = 0; j < 4; ++j)
        if (rows[j] >= 0) pos[j] = atomicAdd(&cnt[rows[j] * CSTR], 1);
#pragma unroll
    for (int j = 0; j < 4; ++j) {
        if (rows[j] < 0) continue;
        if (pos[j] < CAP) {
            bkt[rows[j] * CAP + pos[j]] = cols[j];
        } else {                                   // ~never: exact fallback
            float* op = out + (long long)rows[j] * H;
            const unsigned short* hp = hb + (long long)cols[j] * H;
            for (int c = 0; c < H; ++c) atomicAdd(op + c, bf2f(hp[c]));
        }
    }
}

// ---------------- pull aggregation: wave per node, 8 gathers in flight ----------------
__global__ __launch_bounds__(256) void aggr_kernel(
    const int* __restrict__ cnt, const int* __restrict__ bkt,
    const unsigned short* __restrict__ hb, float* __restrict__ out)
{
    int lane = threadIdx.x & 63;
    int node = blockIdx.x * (blockDim.x >> 6) + (threadIdx.x >> 6);
    if (node >= N_NODES) return;

    int m = cnt[node * CSTR];
    if (m > CAP) m = CAP;
    const int* b = bkt + node * CAP;

    float acc = 0.0f;
    for (int i0 = 0; i0 < m; i0 += 8) {
        int4 c0 = *(const int4*)(b + i0);          // uniform 16B loads
        int4 c1 = *(const int4*)(b + i0 + 4);
        int cols[8] = {c0.x, c0.y, c0.z, c0.w, c1.x, c1.y, c1.z, c1.w};
        int mm = m - i0;
        float v[8];
#pragma unroll
        for (int j = 0; j < 8; ++j)                // 8 independent gathers in flight
            if (j < mm) v[j] = bf2f(hb[(long long)cols[j] * H + lane]);
#pragma unroll
        for (int j = 0; j < 8; ++j)
            if (j < mm) acc += v[j];
    }
    out[(long long)node * H + lane] += acc;        // out already holds fp32 self term
}

extern "C" void kernel_launch(void* const* d_in, const int* in_sizes, int n_in,
                              void* d_out, int out_size, void* d_ws, size_t ws_size,
                              hipStream_t stream)
{
    const float* x   = (const float*)d_in[0];
    const int*   ei  = (const int*)d_in[1];
    const float* W1  = (const float*)d_in[2];
    const float* b1  = (const float*)d_in[3];
    const float* g1  = (const float*)d_in[4];
    const float* be1 = (const float*)d_in[5];
    const float* W2  = (const float*)d_in[6];
    const float* b2  = (const float*)d_in[7];
    const float* g2  = (const float*)d_in[8];
    const float* be2 = (const float*)d_in[9];

    float* out = (float*)d_out;

    // workspace layout (32 MB total)
    char* ws = (char*)d_ws;
    unsigned short* hb  = (unsigned short*)ws;         // 12,800,000 B
    int*            cnt = (int*)(ws + 12800000);       //  6,400,000 B (100000*16*4)
    int*            bkt = (int*)(ws + 19200000);       // 12,800,000 B

    const int E = in_sizes[1] / 2;

    hipMemsetAsync(cnt, 0, (size_t)N_NODES * CSTR * 4, stream);

    mlp_kernel<<<(N_NODES + 255) / 256, 256, 0, stream>>>(
        x, W1, b1, g1, be1, W2, b2, g2, be2, hb, out);

    int sthreads = (E + 3) / 4;
    scatter_kernel<<<(sthreads + 255) / 256, 256, 0, stream>>>(ei, hb, cnt, bkt, out, E);

    aggr_kernel<<<(N_NODES + 3) / 4, 256, 0, stream>>>(cnt, bkt, hb, out);
}

// Round 5
// 290.056 us; speedup vs baseline: 2.4622x; 1.1590x over previous
//
#include <hip/hip_runtime.h>

#define N_NODES 100000
#define D_IN 32
#define H 64
#define EPS 1e-5f
#define CAP 32      // bucket capacity; P(Poisson(12.5) > 32) ~ 1e-6/node
#define CSTR 16     // counter stride (ints): one counter per 64B line
#define OV_CAP 32768

__device__ __forceinline__ unsigned short f2bf(float f) {
    union { float f; unsigned int u; } c; c.f = f;
    unsigned int b = c.u + 0x7FFFu + ((c.u >> 16) & 1u);   // RNE
    return (unsigned short)(b >> 16);
}
__device__ __forceinline__ float bf2f(unsigned short s) {
    union { unsigned int u; float f; } c; c.u = ((unsigned int)s) << 16;
    return c.f;
}

// ---------------- node MLP: thread-per-node ----------------
// __launch_bounds__(256,2): 256-VGPR budget so h1[64]+h2[64] live set stays
// in registers (R4 spilled ~50MB at VGPR=72). Writes bf16 hb only; aggr
// composes the final out = self + aggr.
__global__ __launch_bounds__(256, 2) void mlp_kernel(
    const float* __restrict__ x,
    const float* __restrict__ W1, const float* __restrict__ b1,
    const float* __restrict__ g1, const float* __restrict__ be1,
    const float* __restrict__ W2, const float* __restrict__ b2,
    const float* __restrict__ g2, const float* __restrict__ be2,
    unsigned short* __restrict__ hb)
{
    int gid = blockIdx.x * blockDim.x + threadIdx.x;
    int node = gid < N_NODES ? gid : N_NODES - 1;   // uniform CF (scalarizable W loads)

    float xr[D_IN];
    {
        const float4* xp = (const float4*)(x + (long long)node * D_IN);
#pragma unroll
        for (int i = 0; i < D_IN / 4; ++i) {
            float4 v = xp[i];
            xr[4*i+0] = v.x; xr[4*i+1] = v.y; xr[4*i+2] = v.z; xr[4*i+3] = v.w;
        }
    }

    float h1[H];
#pragma unroll
    for (int jb = 0; jb < H / 4; ++jb) {
        float4 b = *(const float4*)(b1 + jb * 4);
        h1[4*jb+0] = b.x; h1[4*jb+1] = b.y; h1[4*jb+2] = b.z; h1[4*jb+3] = b.w;
    }
#pragma unroll
    for (int k = 0; k < D_IN; ++k) {
        float xk = xr[k];
#pragma unroll
        for (int jb = 0; jb < H / 4; ++jb) {
            float4 w = *(const float4*)(W1 + k * H + jb * 4);
            h1[4*jb+0] += xk * w.x; h1[4*jb+1] += xk * w.y;
            h1[4*jb+2] += xk * w.z; h1[4*jb+3] += xk * w.w;
        }
    }
    {
        float s0=0,s1=0,s2=0,s3=0, q0=0,q1=0,q2=0,q3=0;
#pragma unroll
        for (int j = 0; j < H; j += 4) {
            s0 += h1[j+0]; s1 += h1[j+1]; s2 += h1[j+2]; s3 += h1[j+3];
            q0 += h1[j+0]*h1[j+0]; q1 += h1[j+1]*h1[j+1];
            q2 += h1[j+2]*h1[j+2]; q3 += h1[j+3]*h1[j+3];
        }
        float mu  = (s0+s1+s2+s3) * (1.0f / H);
        float var = (q0+q1+q2+q3) * (1.0f / H) - mu * mu;
        float rs  = rsqrtf(var + EPS);
#pragma unroll
        for (int jb = 0; jb < H / 4; ++jb) {
            float4 g = *(const float4*)(g1 + jb * 4);
            float4 be = *(const float4*)(be1 + jb * 4);
            h1[4*jb+0] = fmaxf((h1[4*jb+0]-mu)*rs*g.x + be.x, 0.0f);
            h1[4*jb+1] = fmaxf((h1[4*jb+1]-mu)*rs*g.y + be.y, 0.0f);
            h1[4*jb+2] = fmaxf((h1[4*jb+2]-mu)*rs*g.z + be.z, 0.0f);
            h1[4*jb+3] = fmaxf((h1[4*jb+3]-mu)*rs*g.w + be.w, 0.0f);
        }
    }

    float h2[H];
#pragma unroll
    for (int jb = 0; jb < H / 4; ++jb) {
        float4 b = *(const float4*)(b2 + jb * 4);
        h2[4*jb+0] = b.x; h2[4*jb+1] = b.y; h2[4*jb+2] = b.z; h2[4*jb+3] = b.w;
    }
#pragma unroll
    for (int k = 0; k < H; ++k) {
        float hk = h1[k];
#pragma unroll
        for (int jb = 0; jb < H / 4; ++jb) {
            float4 w = *(const float4*)(W2 + k * H + jb * 4);
            h2[4*jb+0] += hk * w.x; h2[4*jb+1] += hk * w.y;
            h2[4*jb+2] += hk * w.z; h2[4*jb+3] += hk * w.w;
        }
    }
    {
        float s0=0,s1=0,s2=0,s3=0, q0=0,q1=0,q2=0,q3=0;
#pragma unroll
        for (int j = 0; j < H; j += 4) {
            s0 += h2[j+0]; s1 += h2[j+1]; s2 += h2[j+2]; s3 += h2[j+3];
            q0 += h2[j+0]*h2[j+0]; q1 += h2[j+1]*h2[j+1];
            q2 += h2[j+2]*h2[j+2]; q3 += h2[j+3]*h2[j+3];
        }
        float mu  = (s0+s1+s2+s3) * (1.0f / H);
        float var = (q0+q1+q2+q3) * (1.0f / H) - mu * mu;
        float rs  = rsqrtf(var + EPS);

        unsigned short* hp = hb + (long long)node * H;
#pragma unroll
        for (int jb = 0; jb < H / 4; ++jb) {
            float4 g = *(const float4*)(g2 + jb * 4);
            float4 be = *(const float4*)(be2 + jb * 4);
            ushort4 u;
            u.x = f2bf(fmaxf((h2[4*jb+0]-mu)*rs*g.x + be.x, 0.0f));
            u.y = f2bf(fmaxf((h2[4*jb+1]-mu)*rs*g.y + be.y, 0.0f));
            u.z = f2bf(fmaxf((h2[4*jb+2]-mu)*rs*g.z + be.z, 0.0f));
            u.w = f2bf(fmaxf((h2[4*jb+3]-mu)*rs*g.w + be.w, 0.0f));
            *(ushort4*)(hp + 4*jb) = u;
        }
    }
}

// ---------------- edge scatter: 8 edges/thread, line-padded counters ----------------
__global__ __launch_bounds__(256) void scatter_kernel(
    const int* __restrict__ ei,
    int* __restrict__ cnt, int* __restrict__ bkt,
    int* __restrict__ ovCnt, int2* __restrict__ ov, int E)
{
    int t = blockIdx.x * blockDim.x + threadIdx.x;
    int e0 = t * 8;
    if (e0 >= E) return;

    int rows[8], cols[8], pos[8];
    if (e0 + 7 < E) {
        int4 r0 = *(const int4*)(ei + e0);
        int4 r1 = *(const int4*)(ei + e0 + 4);
        int4 c0 = *(const int4*)(ei + E + e0);
        int4 c1 = *(const int4*)(ei + E + e0 + 4);
        rows[0]=r0.x; rows[1]=r0.y; rows[2]=r0.z; rows[3]=r0.w;
        rows[4]=r1.x; rows[5]=r1.y; rows[6]=r1.z; rows[7]=r1.w;
        cols[0]=c0.x; cols[1]=c0.y; cols[2]=c0.z; cols[3]=c0.w;
        cols[4]=c1.x; cols[5]=c1.y; cols[6]=c1.z; cols[7]=c1.w;
    } else {
#pragma unroll
        for (int j = 0; j < 8; ++j) {
            int e = e0 + j;
            if (e < E) { rows[j] = ei[e]; cols[j] = ei[E + e]; }
            else rows[j] = -1;
        }
    }
    // 8 independent returning atomics in flight
#pragma unroll
    for (int j = 0; j < 8; ++j)
        if (rows[j] >= 0) pos[j] = atomicAdd(&cnt[rows[j] * CSTR], 1);
#pragma unroll
    for (int j = 0; j < 8; ++j) {
        if (rows[j] < 0) continue;
        if (pos[j] < CAP) {
            bkt[rows[j] * CAP + pos[j]] = cols[j];
        } else {                                    // exact overflow list (~never)
            int s = atomicAdd(ovCnt, 1);
            if (s < OV_CAP) ov[s] = make_int2(rows[j], cols[j]);
        }
    }
}

// ---------------- pull aggregation: wave per node, 8 gathers in flight ----------------
__global__ __launch_bounds__(256) void aggr_kernel(
    const int* __restrict__ cnt, const int* __restrict__ bkt,
    const unsigned short* __restrict__ hb, float* __restrict__ out,
    const int* __restrict__ ovCnt, const int2* __restrict__ ov)
{
    int lane = threadIdx.x & 63;
    int node = blockIdx.x * (blockDim.x >> 6) + (threadIdx.x >> 6);
    if (node >= N_NODES) return;

    int m = cnt[node * CSTR];
    if (m > CAP) m = CAP;
    const int* b = bkt + node * CAP;

    float acc = 0.0f;
    for (int i0 = 0; i0 < m; i0 += 8) {
        int4 c0 = *(const int4*)(b + i0);
        int4 c1 = *(const int4*)(b + i0 + 4);
        int cols[8] = {c0.x, c0.y, c0.z, c0.w, c1.x, c1.y, c1.z, c1.w};
        int mm = m - i0;
        float v[8];
#pragma unroll
        for (int j = 0; j < 8; ++j)
            if (j < mm) v[j] = bf2f(hb[cols[j] * H + lane]);
#pragma unroll
        for (int j = 0; j < 8; ++j)
            if (j < mm) acc += v[j];
    }

    // exact overflow drain (normally ovCnt == 0)
    int nov = *ovCnt; if (nov > OV_CAP) nov = OV_CAP;
    for (int i = 0; i < nov; ++i) {
        int2 rc = ov[i];
        if (rc.x == node) acc += bf2f(hb[rc.y * H + lane]);
    }

    out[node * H + lane] = bf2f(hb[node * H + lane]) + acc;
}

extern "C" void kernel_launch(void* const* d_in, const int* in_sizes, int n_in,
                              void* d_out, int out_size, void* d_ws, size_t ws_size,
                              hipStream_t stream)
{
    const float* x   = (const float*)d_in[0];
    const int*   ei  = (const int*)d_in[1];
    const float* W1  = (const float*)d_in[2];
    const float* b1  = (const float*)d_in[3];
    const float* g1  = (const float*)d_in[4];
    const float* be1 = (const float*)d_in[5];
    const float* W2  = (const float*)d_in[6];
    const float* b2  = (const float*)d_in[7];
    const float* g2  = (const float*)d_in[8];
    const float* be2 = (const float*)d_in[9];

    float* out = (float*)d_out;

    // workspace layout (~32.3 MB)
    char* ws = (char*)d_ws;
    unsigned short* hb    = (unsigned short*)ws;        // 12,800,000 B
    int*            cnt   = (int*)(ws + 12800000);      //  6,400,000 B
    int*            ovCnt = (int*)(ws + 19200000);      //         64 B (zeroed with cnt)
    int2*           ov    = (int2*)(ws + 19200064);     //    262,144 B
    int*            bkt   = (int*)(ws + 19462208);      // 12,800,000 B

    const int E = in_sizes[1] / 2;

    hipMemsetAsync(cnt, 0, 6400064, stream);            // cnt + ovCnt

    mlp_kernel<<<(N_NODES + 255) / 256, 256, 0, stream>>>(
        x, W1, b1, g1, be1, W2, b2, g2, be2, hb);

    int sthreads = (E + 7) / 8;
    scatter_kernel<<<(sthreads + 255) / 256, 256, 0, stream>>>(ei, cnt, bkt, ovCnt, ov, E);

    aggr_kernel<<<(N_NODES + 3) / 4, 256, 0, stream>>>(cnt, bkt, hb, out, ovCnt, ov);
}